// Round 8
// baseline (268.790 us; speedup 1.0000x reference)
//
#include <hip/hip_runtime.h>
#include <math.h>

#define N_IMG 16
#define CCH   64
#define H     256
#define W     256
#define HW    (H*W)      // 65536
#define HW4   (HW/4)     // 16384
#define TS    16

typedef float fx4 __attribute__((ext_vector_type(4)));

// -------- Kernel 1: fused gray (halo recompute) + 7 convs + partials --------
// Grid: (16,16,16) tiles; each block builds its own 22x22 gray tile from x.
__global__ __launch_bounds__(256) void grayconv_kernel(const float* __restrict__ x,
                                                       float* __restrict__ comb,
                                                       float2* __restrict__ part) {
    __shared__ float t[22][23];
    __shared__ float rs[256];
    __shared__ float rq[256];
    int n  = blockIdx.z;
    int h0 = blockIdx.y * TS - 3;
    int w0 = blockIdx.x * TS - 3;
    const float* xn = x + (size_t)n * CCH * HW;

    int tid = threadIdx.y * TS + threadIdx.x;

    // Build gray halo tile: 484 pixels, each = mean over 64 channels.
    for (int i = tid; i < 22 * 22; i += 256) {
        int r  = i / 22, c2 = i - r * 22;
        int hh = h0 + r, ww = w0 + c2;
        float s = 0.f;
        if (hh >= 0 && hh < H && ww >= 0 && ww < W) {
            const float* p = xn + (size_t)hh * W + ww;
            float s0 = 0.f, s1 = 0.f, s2 = 0.f, s3 = 0.f;
            #pragma unroll
            for (int ch = 0; ch < CCH; ch += 4) {
                s0 += p[(size_t)(ch + 0) * HW];
                s1 += p[(size_t)(ch + 1) * HW];
                s2 += p[(size_t)(ch + 2) * HW];
                s3 += p[(size_t)(ch + 3) * HW];
            }
            s = (s0 + s1 + s2 + s3) * (1.0f / 64.0f);
        }
        t[r][c2] = s;
    }
    __syncthreads();

    int ty = threadIdx.y, tx = threadIdx.x;
    float v[7][7];
    #pragma unroll
    for (int i = 0; i < 7; ++i)
        #pragma unroll
        for (int j = 0; j < 7; ++j)
            v[i][j] = t[ty + i][tx + j];

    float gx7 = 0.f, gy7 = 0.f;
    {
        const float vw[7] = {1.f, 6.f, 15.f, 20.f, 15.f, 6.f, 1.f};
        const float dw[7] = {-1.f, -4.f, -5.f, 0.f, 5.f, 4.f, 1.f};
        #pragma unroll
        for (int i = 0; i < 7; ++i) {
            float rh  = -v[i][0] - 4.f*v[i][1] - 5.f*v[i][2] + 5.f*v[i][4] + 4.f*v[i][5] + v[i][6];
            float rsu =  v[i][0] + 6.f*v[i][1] + 15.f*v[i][2] + 20.f*v[i][3] + 15.f*v[i][4] + 6.f*v[i][5] + v[i][6];
            gx7 += vw[i] * rh;
            gy7 += dw[i] * rsu;
        }
    }
    float gx5 = 0.f, gy5 = 0.f;
    {
        const float vw[5] = {1.f, 4.f, 6.f, 4.f, 1.f};
        const float dw[5] = {-1.f, -2.f, 0.f, 2.f, 1.f};
        #pragma unroll
        for (int i = 0; i < 5; ++i) {
            float rh  = -v[i+1][1] - 2.f*v[i+1][2] + 2.f*v[i+1][4] + v[i+1][5];
            float rsu =  v[i+1][1] + 4.f*v[i+1][2] + 6.f*v[i+1][3] + 4.f*v[i+1][4] + v[i+1][5];
            gx5 += vw[i] * rh;
            gy5 += dw[i] * rsu;
        }
    }
    float gx3 = 0.f, gy3 = 0.f;
    {
        const float vw[3] = {1.f, 2.f, 1.f};
        const float dw[3] = {-1.f, 0.f, 1.f};
        #pragma unroll
        for (int i = 0; i < 3; ++i) {
            float rh  = v[i+2][4] - v[i+2][2];
            float rsu = v[i+2][2] + 2.f*v[i+2][3] + v[i+2][4];
            gx3 += vw[i] * rh;
            gy3 += dw[i] * rsu;
        }
    }
    float lap = v[2][3] + v[4][3] + v[3][2] + v[3][4] - 4.f*v[3][3];

    float e3 = sqrtf(gx3*gx3 + gy3*gy3 + 1e-6f);
    float e5 = sqrtf(gx5*gx5 + gy5*gy5 + 1e-6f);
    float e7 = sqrtf(gx7*gx7 + gy7*gy7 + 1e-6f);
    float combined = (e3 + e5 + e7 + fabsf(lap)) * 0.25f;

    comb[(size_t)n * HW + (size_t)(h0 + 3 + ty) * W + (w0 + 3 + tx)] = combined;

    rs[tid] = combined;
    rq[tid] = combined * combined;
    __syncthreads();
    for (int off = 128; off > 0; off >>= 1) {
        if (tid < off) {
            rs[tid] += rs[tid + off];
            rq[tid] += rq[tid + off];
        }
        __syncthreads();
    }
    if (tid == 0) {
        int blockLin = blockIdx.y * (W / TS) + blockIdx.x;   // 0..255
        part[n * 256 + blockLin] = make_float2(rs[0], rq[0]);
    }
}

// ------- Kernel 2: stats finalize (redundant per block) + gate + multiply -------
// Grid: 2048 blocks = 16 img x 2 ch-halves x 64 pixel-groups.
__global__ __launch_bounds__(256) void mul_kernel(const float4* __restrict__ x,
                                                  const float4* __restrict__ comb4,
                                                  const float2* __restrict__ part,
                                                  fx4* __restrict__ out) {
    __shared__ float rs[256];
    __shared__ float rq[256];
    int bid  = blockIdx.x;
    int n    = bid >> 7;                 // image
    int rest = bid & 127;
    int half = rest >> 6;                // channel half: 0 or 1
    int p4   = ((rest & 63) << 8) + threadIdx.x;   // float4-pixel in image
    int tid  = threadIdx.x;

    float2 p = part[n * 256 + tid];
    rs[tid] = p.x;
    rq[tid] = p.y;
    __syncthreads();
    for (int off = 128; off > 0; off >>= 1) {
        if (tid < off) {
            rs[tid] += rs[tid + off];
            rq[tid] += rq[tid + off];
        }
        __syncthreads();
    }
    float mu  = rs[0] / (float)HW;
    float var = (rq[0] - (float)HW * mu * mu) / (float)(HW - 1);
    var = fmaxf(var, 0.f);
    float inv = 1.0f / (sqrtf(var) + 1e-6f);

    float4 c = comb4[((size_t)n << 14) + p4];
    fx4 f;
    f.x = 1.0f + 1.0f / (1.0f + __expf(2.5f - 5.0f * (c.x - mu) * inv));
    f.y = 1.0f + 1.0f / (1.0f + __expf(2.5f - 5.0f * (c.y - mu) * inv));
    f.z = 1.0f + 1.0f / (1.0f + __expf(2.5f - 5.0f * (c.z - mu) * inv));
    f.w = 1.0f + 1.0f / (1.0f + __expf(2.5f - 5.0f * (c.w - mu) * inv));

    const int ch0 = half * 32;
    const float4* xp = x   + (size_t)n * CCH * HW4 + (size_t)ch0 * HW4 + p4;
    fx4*          op = out + (size_t)n * CCH * HW4 + (size_t)ch0 * HW4 + p4;
    #pragma unroll 8
    for (int ch = 0; ch < 32; ++ch) {
        float4 v = xp[(size_t)ch * HW4];
        fx4 r;
        r.x = v.x * f.x;
        r.y = v.y * f.y;
        r.z = v.z * f.z;
        r.w = v.w * f.w;
        __builtin_nontemporal_store(r, &op[(size_t)ch * HW4]);
    }
}

extern "C" void kernel_launch(void* const* d_in, const int* in_sizes, int n_in,
                              void* d_out, int out_size, void* d_ws, size_t ws_size,
                              hipStream_t stream) {
    const float* x = (const float*)d_in[0];
    float* out = (float*)d_out;
    char* ws = (char*)d_ws;

    float*  comb  = (float*)ws;                                    // 4 MiB
    float2* part  = (float2*)(ws + (size_t)N_IMG * HW * 4);        // 32 KiB

    dim3 cgrid(W / TS, H / TS, N_IMG);
    grayconv_kernel<<<cgrid, dim3(TS, TS), 0, stream>>>(x, comb, part);

    mul_kernel<<<N_IMG * 128, 256, 0, stream>>>((const float4*)x, (const float4*)comb,
                                                part, (fx4*)out);
}

// Round 9
// 256.303 us; speedup vs baseline: 1.0487x; 1.0487x over previous
//
#include <hip/hip_runtime.h>
#include <math.h>

#define N_IMG 16
#define CCH   64
#define H     256
#define W     256
#define HW    (H*W)      // 65536
#define HW4   (HW/4)     // 16384
#define TS    16

typedef float fx4 __attribute__((ext_vector_type(4)));

// ---------------- Kernel 1: gray = mean over channels ----------------
__global__ __launch_bounds__(256) void gray_kernel(const float4* __restrict__ x,
                                                   float4* __restrict__ gray) {
    int bid = blockIdx.x;              // 16*64 = 1024 blocks
    int n   = bid >> 6;
    int p4  = ((bid & 63) << 8) + threadIdx.x;   // 0..16383
    const float4* xp = x + (size_t)n * CCH * HW4 + p4;
    float4 a0 = make_float4(0.f, 0.f, 0.f, 0.f);
    float4 a1 = a0, a2 = a0, a3 = a0;
    #pragma unroll
    for (int c = 0; c < CCH; c += 4) {
        float4 v0 = xp[(size_t)(c + 0) * HW4];
        float4 v1 = xp[(size_t)(c + 1) * HW4];
        float4 v2 = xp[(size_t)(c + 2) * HW4];
        float4 v3 = xp[(size_t)(c + 3) * HW4];
        a0.x += v0.x; a0.y += v0.y; a0.z += v0.z; a0.w += v0.w;
        a1.x += v1.x; a1.y += v1.y; a1.z += v1.z; a1.w += v1.w;
        a2.x += v2.x; a2.y += v2.y; a2.z += v2.z; a2.w += v2.w;
        a3.x += v3.x; a3.y += v3.y; a3.z += v3.z; a3.w += v3.w;
    }
    const float s = 1.0f / 64.0f;
    float4 acc;
    acc.x = (a0.x + a1.x + a2.x + a3.x) * s;
    acc.y = (a0.y + a1.y + a2.y + a3.y) * s;
    acc.z = (a0.z + a1.z + a2.z + a3.z) * s;
    acc.w = (a0.w + a1.w + a2.w + a3.w) * s;
    gray[(size_t)n * HW4 + p4] = acc;
}

// ---- Kernel 2: 7 convs + edge combine + partials + last-arriver stats ----
__global__ __launch_bounds__(256) void conv_kernel(const float* __restrict__ gray,
                                                   float* __restrict__ comb,
                                                   float2* __restrict__ part,
                                                   float2* __restrict__ stats,
                                                   unsigned* __restrict__ cnt) {
    __shared__ float t[TS + 6][TS + 7];   // 22 x 23
    __shared__ float rs[256];
    __shared__ float rq[256];
    __shared__ int sIsLast;
    int n  = blockIdx.z;
    int h0 = blockIdx.y * TS - 3;
    int w0 = blockIdx.x * TS - 3;
    const float* g = gray + (size_t)n * HW;

    int tid = threadIdx.y * TS + threadIdx.x;
    for (int i = tid; i < 22 * 22; i += 256) {
        int r  = i / 22, c2 = i - r * 22;
        int hh = h0 + r, ww = w0 + c2;
        t[r][c2] = (hh >= 0 && hh < H && ww >= 0 && ww < W) ? g[hh * W + ww] : 0.f;
    }
    __syncthreads();

    int ty = threadIdx.y, tx = threadIdx.x;
    float v[7][7];
    #pragma unroll
    for (int i = 0; i < 7; ++i)
        #pragma unroll
        for (int j = 0; j < 7; ++j)
            v[i][j] = t[ty + i][tx + j];

    float gx7 = 0.f, gy7 = 0.f;
    {
        const float vw[7] = {1.f, 6.f, 15.f, 20.f, 15.f, 6.f, 1.f};
        const float dw[7] = {-1.f, -4.f, -5.f, 0.f, 5.f, 4.f, 1.f};
        #pragma unroll
        for (int i = 0; i < 7; ++i) {
            float rh  = -v[i][0] - 4.f*v[i][1] - 5.f*v[i][2] + 5.f*v[i][4] + 4.f*v[i][5] + v[i][6];
            float rsu =  v[i][0] + 6.f*v[i][1] + 15.f*v[i][2] + 20.f*v[i][3] + 15.f*v[i][4] + 6.f*v[i][5] + v[i][6];
            gx7 += vw[i] * rh;
            gy7 += dw[i] * rsu;
        }
    }
    float gx5 = 0.f, gy5 = 0.f;
    {
        const float vw[5] = {1.f, 4.f, 6.f, 4.f, 1.f};
        const float dw[5] = {-1.f, -2.f, 0.f, 2.f, 1.f};
        #pragma unroll
        for (int i = 0; i < 5; ++i) {
            float rh  = -v[i+1][1] - 2.f*v[i+1][2] + 2.f*v[i+1][4] + v[i+1][5];
            float rsu =  v[i+1][1] + 4.f*v[i+1][2] + 6.f*v[i+1][3] + 4.f*v[i+1][4] + v[i+1][5];
            gx5 += vw[i] * rh;
            gy5 += dw[i] * rsu;
        }
    }
    float gx3 = 0.f, gy3 = 0.f;
    {
        const float vw[3] = {1.f, 2.f, 1.f};
        const float dw[3] = {-1.f, 0.f, 1.f};
        #pragma unroll
        for (int i = 0; i < 3; ++i) {
            float rh  = v[i+2][4] - v[i+2][2];
            float rsu = v[i+2][2] + 2.f*v[i+2][3] + v[i+2][4];
            gx3 += vw[i] * rh;
            gy3 += dw[i] * rsu;
        }
    }
    float lap = v[2][3] + v[4][3] + v[3][2] + v[3][4] - 4.f*v[3][3];

    float e3 = sqrtf(gx3*gx3 + gy3*gy3 + 1e-6f);
    float e5 = sqrtf(gx5*gx5 + gy5*gy5 + 1e-6f);
    float e7 = sqrtf(gx7*gx7 + gy7*gy7 + 1e-6f);
    float combined = (e3 + e5 + e7 + fabsf(lap)) * 0.25f;

    comb[(size_t)n * HW + (size_t)(h0 + 3 + ty) * W + (w0 + 3 + tx)] = combined;

    rs[tid] = combined;
    rq[tid] = combined * combined;
    __syncthreads();
    for (int off = 128; off > 0; off >>= 1) {
        if (tid < off) {
            rs[tid] += rs[tid + off];
            rq[tid] += rq[tid + off];
        }
        __syncthreads();
    }
    if (tid == 0) {
        int blockLin = blockIdx.y * (W / TS) + blockIdx.x;   // 0..255
        part[n * 256 + blockLin] = make_float2(rs[0], rq[0]);
        __threadfence();                                     // publish partial
        unsigned old = atomicAdd(&cnt[n], 1u);               // device-scope
        sIsLast = (old == 255u);
    }
    __syncthreads();

    // Last block of this image finalizes stats (fixed-order tree -> deterministic)
    if (sIsLast) {
        __threadfence();                  // acquire: see all 256 partials
        float2 p = part[n * 256 + tid];
        rs[tid] = p.x;
        rq[tid] = p.y;
        __syncthreads();
        for (int off = 128; off > 0; off >>= 1) {
            if (tid < off) {
                rs[tid] += rs[tid + off];
                rq[tid] += rq[tid + off];
            }
            __syncthreads();
        }
        if (tid == 0) {
            float mu  = rs[0] / (float)HW;
            float var = (rq[0] - (float)HW * mu * mu) / (float)(HW - 1);
            var = fmaxf(var, 0.f);
            stats[n] = make_float2(mu, 1.0f / (sqrtf(var) + 1e-6f));
        }
    }
}

// ------- Kernel 3: gate + multiply. 4096 blocks = 16 img x 4 ch-quarters x 64 pgroups -------
__global__ __launch_bounds__(256) void mul_kernel(const fx4* __restrict__ x,
                                                  const float4* __restrict__ comb4,
                                                  const float2* __restrict__ stats,
                                                  fx4* __restrict__ out) {
    int bid = blockIdx.x;
    int n   = bid >> 8;                        // image
    int q   = (bid >> 6) & 3;                  // channel quarter
    int p4  = ((bid & 63) << 8) + threadIdx.x; // float4-pixel in image

    float2 st = stats[n];
    float mu = st.x, inv = st.y;

    float4 c = comb4[((size_t)n << 14) + p4];
    fx4 f;
    f.x = 1.0f + 1.0f / (1.0f + __expf(2.5f - 5.0f * (c.x - mu) * inv));
    f.y = 1.0f + 1.0f / (1.0f + __expf(2.5f - 5.0f * (c.y - mu) * inv));
    f.z = 1.0f + 1.0f / (1.0f + __expf(2.5f - 5.0f * (c.z - mu) * inv));
    f.w = 1.0f + 1.0f / (1.0f + __expf(2.5f - 5.0f * (c.w - mu) * inv));

    const int ch0 = q * 16;
    const fx4* xp = x   + (size_t)n * CCH * HW4 + (size_t)ch0 * HW4 + p4;
    fx4*       op = out + (size_t)n * CCH * HW4 + (size_t)ch0 * HW4 + p4;
    #pragma unroll
    for (int ch = 0; ch < 16; ++ch) {
        fx4 v = __builtin_nontemporal_load(&xp[(size_t)ch * HW4]);
        fx4 r = v * f;
        __builtin_nontemporal_store(r, &op[(size_t)ch * HW4]);
    }
}

extern "C" void kernel_launch(void* const* d_in, const int* in_sizes, int n_in,
                              void* d_out, int out_size, void* d_ws, size_t ws_size,
                              hipStream_t stream) {
    const float* x = (const float*)d_in[0];
    float* out = (float*)d_out;
    char* ws = (char*)d_ws;

    float*    gray  = (float*)ws;                                  // 4 MiB
    float*    comb  = (float*)(ws + (size_t)N_IMG * HW * 4);       // 4 MiB
    float2*   part  = (float2*)(ws + (size_t)2 * N_IMG * HW * 4);  // 32 KiB
    float2*   stats = (float2*)((char*)part + 4096 * sizeof(float2));
    unsigned* cnt   = (unsigned*)((char*)stats + N_IMG * sizeof(float2));

    hipMemsetAsync(cnt, 0, N_IMG * sizeof(unsigned), stream);

    gray_kernel<<<N_IMG * 64, 256, 0, stream>>>((const float4*)x, (float4*)gray);

    dim3 cgrid(W / TS, H / TS, N_IMG);
    conv_kernel<<<cgrid, dim3(TS, TS), 0, stream>>>(gray, comb, part, stats, cnt);

    mul_kernel<<<N_IMG * 256, 256, 0, stream>>>((const fx4*)x, (const float4*)comb,
                                                stats, (fx4*)out);
}

// Round 10
// 140.905 us; speedup vs baseline: 1.9076x; 1.8190x over previous
//
#include <hip/hip_runtime.h>
#include <math.h>

#define N_IMG 16
#define CCH   64
#define H     256
#define W     256
#define HW    (H*W)      // 65536
#define HW4   (HW/4)     // 16384
#define TS    16

typedef float fx4 __attribute__((ext_vector_type(4)));

// ---------------- Kernel 1: gray = mean over channels ----------------
__global__ __launch_bounds__(256) void gray_kernel(const float4* __restrict__ x,
                                                   float4* __restrict__ gray) {
    int bid = blockIdx.x;              // 16*64 = 1024 blocks
    int n   = bid >> 6;
    int p4  = ((bid & 63) << 8) + threadIdx.x;   // 0..16383
    const float4* xp = x + (size_t)n * CCH * HW4 + p4;
    float4 a0 = make_float4(0.f, 0.f, 0.f, 0.f);
    float4 a1 = a0, a2 = a0, a3 = a0;
    #pragma unroll
    for (int c = 0; c < CCH; c += 4) {
        float4 v0 = xp[(size_t)(c + 0) * HW4];
        float4 v1 = xp[(size_t)(c + 1) * HW4];
        float4 v2 = xp[(size_t)(c + 2) * HW4];
        float4 v3 = xp[(size_t)(c + 3) * HW4];
        a0.x += v0.x; a0.y += v0.y; a0.z += v0.z; a0.w += v0.w;
        a1.x += v1.x; a1.y += v1.y; a1.z += v1.z; a1.w += v1.w;
        a2.x += v2.x; a2.y += v2.y; a2.z += v2.z; a2.w += v2.w;
        a3.x += v3.x; a3.y += v3.y; a3.z += v3.z; a3.w += v3.w;
    }
    const float s = 1.0f / 64.0f;
    float4 acc;
    acc.x = (a0.x + a1.x + a2.x + a3.x) * s;
    acc.y = (a0.y + a1.y + a2.y + a3.y) * s;
    acc.z = (a0.z + a1.z + a2.z + a3.z) * s;
    acc.w = (a0.w + a1.w + a2.w + a3.w) * s;
    gray[(size_t)n * HW4 + p4] = acc;
}

// ---------------- Kernel 2: 7 convs + edge combine + per-block stats partials ----------------
__global__ __launch_bounds__(256) void conv_kernel(const float* __restrict__ gray,
                                                   float* __restrict__ comb,
                                                   float2* __restrict__ part) {
    __shared__ float t[TS + 6][TS + 7];   // 22 x 23
    __shared__ float wsum[4];
    __shared__ float wsq[4];
    int n  = blockIdx.z;
    int h0 = blockIdx.y * TS - 3;
    int w0 = blockIdx.x * TS - 3;
    const float* g = gray + (size_t)n * HW;

    int tid = threadIdx.y * TS + threadIdx.x;
    for (int i = tid; i < 22 * 22; i += 256) {
        int r  = i / 22, c2 = i - r * 22;
        int hh = h0 + r, ww = w0 + c2;
        t[r][c2] = (hh >= 0 && hh < H && ww >= 0 && ww < W) ? g[hh * W + ww] : 0.f;
    }
    __syncthreads();

    int ty = threadIdx.y, tx = threadIdx.x;
    float v[7][7];
    #pragma unroll
    for (int i = 0; i < 7; ++i)
        #pragma unroll
        for (int j = 0; j < 7; ++j)
            v[i][j] = t[ty + i][tx + j];

    float gx7 = 0.f, gy7 = 0.f;
    {
        const float vw[7] = {1.f, 6.f, 15.f, 20.f, 15.f, 6.f, 1.f};
        const float dw[7] = {-1.f, -4.f, -5.f, 0.f, 5.f, 4.f, 1.f};
        #pragma unroll
        for (int i = 0; i < 7; ++i) {
            float rh  = -v[i][0] - 4.f*v[i][1] - 5.f*v[i][2] + 5.f*v[i][4] + 4.f*v[i][5] + v[i][6];
            float rsu =  v[i][0] + 6.f*v[i][1] + 15.f*v[i][2] + 20.f*v[i][3] + 15.f*v[i][4] + 6.f*v[i][5] + v[i][6];
            gx7 += vw[i] * rh;
            gy7 += dw[i] * rsu;
        }
    }
    float gx5 = 0.f, gy5 = 0.f;
    {
        const float vw[5] = {1.f, 4.f, 6.f, 4.f, 1.f};
        const float dw[5] = {-1.f, -2.f, 0.f, 2.f, 1.f};
        #pragma unroll
        for (int i = 0; i < 5; ++i) {
            float rh  = -v[i+1][1] - 2.f*v[i+1][2] + 2.f*v[i+1][4] + v[i+1][5];
            float rsu =  v[i+1][1] + 4.f*v[i+1][2] + 6.f*v[i+1][3] + 4.f*v[i+1][4] + v[i+1][5];
            gx5 += vw[i] * rh;
            gy5 += dw[i] * rsu;
        }
    }
    float gx3 = 0.f, gy3 = 0.f;
    {
        const float vw[3] = {1.f, 2.f, 1.f};
        const float dw[3] = {-1.f, 0.f, 1.f};
        #pragma unroll
        for (int i = 0; i < 3; ++i) {
            float rh  = v[i+2][4] - v[i+2][2];
            float rsu = v[i+2][2] + 2.f*v[i+2][3] + v[i+2][4];
            gx3 += vw[i] * rh;
            gy3 += dw[i] * rsu;
        }
    }
    float lap = v[2][3] + v[4][3] + v[3][2] + v[3][4] - 4.f*v[3][3];

    float e3 = sqrtf(gx3*gx3 + gy3*gy3 + 1e-6f);
    float e5 = sqrtf(gx5*gx5 + gy5*gy5 + 1e-6f);
    float e7 = sqrtf(gx7*gx7 + gy7*gy7 + 1e-6f);
    float combined = (e3 + e5 + e7 + fabsf(lap)) * 0.25f;

    comb[(size_t)n * HW + (size_t)(h0 + 3 + ty) * W + (w0 + 3 + tx)] = combined;

    // wave-level butterfly (fixed order, deterministic) + one barrier
    float s = combined, q = combined * combined;
    #pragma unroll
    for (int off = 32; off > 0; off >>= 1) {
        s += __shfl_down(s, off, 64);
        q += __shfl_down(q, off, 64);
    }
    int wave = tid >> 6, lane = tid & 63;
    if (lane == 0) { wsum[wave] = s; wsq[wave] = q; }
    __syncthreads();
    if (tid == 0) {
        float S = ((wsum[0] + wsum[1]) + (wsum[2] + wsum[3]));
        float Q = ((wsq[0]  + wsq[1])  + (wsq[2]  + wsq[3]));
        int blockLin = blockIdx.y * (W / TS) + blockIdx.x;   // 0..255
        part[n * 256 + blockLin] = make_float2(S, Q);
    }
}

// ------- Kernel 3: stats finalize (redundant per block) + gate + multiply -------
// Grid: 2048 blocks = 16 img x 2 ch-halves x 64 pixel-groups.
__global__ __launch_bounds__(256) void mul_kernel(const float4* __restrict__ x,
                                                  const float4* __restrict__ comb4,
                                                  const float2* __restrict__ part,
                                                  fx4* __restrict__ out) {
    __shared__ float wsum[4];
    __shared__ float wsq[4];
    int bid  = blockIdx.x;
    int n    = bid >> 7;                 // image
    int rest = bid & 127;
    int half = rest >> 6;                // channel half: 0 or 1
    int p4   = ((rest & 63) << 8) + threadIdx.x;   // float4-pixel in image
    int tid  = threadIdx.x;

    // Deterministic fixed-order reduce of this image's 256 partials
    float2 p = part[n * 256 + tid];
    float s = p.x, q = p.y;
    #pragma unroll
    for (int off = 32; off > 0; off >>= 1) {
        s += __shfl_down(s, off, 64);
        q += __shfl_down(q, off, 64);
    }
    int wave = tid >> 6, lane = tid & 63;
    if (lane == 0) { wsum[wave] = s; wsq[wave] = q; }
    __syncthreads();
    float S = ((wsum[0] + wsum[1]) + (wsum[2] + wsum[3]));
    float Q = ((wsq[0]  + wsq[1])  + (wsq[2]  + wsq[3]));
    float mu  = S / (float)HW;
    float var = (Q - (float)HW * mu * mu) / (float)(HW - 1);
    var = fmaxf(var, 0.f);
    float inv = 1.0f / (sqrtf(var) + 1e-6f);

    float4 c = comb4[((size_t)n << 14) + p4];
    fx4 f;
    f.x = 1.0f + 1.0f / (1.0f + __expf(2.5f - 5.0f * (c.x - mu) * inv));
    f.y = 1.0f + 1.0f / (1.0f + __expf(2.5f - 5.0f * (c.y - mu) * inv));
    f.z = 1.0f + 1.0f / (1.0f + __expf(2.5f - 5.0f * (c.z - mu) * inv));
    f.w = 1.0f + 1.0f / (1.0f + __expf(2.5f - 5.0f * (c.w - mu) * inv));

    const int ch0 = half * 32;
    const float4* xp = x   + (size_t)n * CCH * HW4 + (size_t)ch0 * HW4 + p4;
    fx4*          op = out + (size_t)n * CCH * HW4 + (size_t)ch0 * HW4 + p4;
    #pragma unroll 8
    for (int ch = 0; ch < 32; ++ch) {
        float4 v = xp[(size_t)ch * HW4];
        fx4 r;
        r.x = v.x * f.x;
        r.y = v.y * f.y;
        r.z = v.z * f.z;
        r.w = v.w * f.w;
        __builtin_nontemporal_store(r, &op[(size_t)ch * HW4]);
    }
}

extern "C" void kernel_launch(void* const* d_in, const int* in_sizes, int n_in,
                              void* d_out, int out_size, void* d_ws, size_t ws_size,
                              hipStream_t stream) {
    const float* x = (const float*)d_in[0];
    float* out = (float*)d_out;
    char* ws = (char*)d_ws;

    float*  gray  = (float*)ws;                                    // 4 MiB
    float*  comb  = (float*)(ws + (size_t)N_IMG * HW * 4);         // 4 MiB
    float2* part  = (float2*)(ws + (size_t)2 * N_IMG * HW * 4);    // 32 KiB

    gray_kernel<<<N_IMG * 64, 256, 0, stream>>>((const float4*)x, (float4*)gray);

    dim3 cgrid(W / TS, H / TS, N_IMG);
    conv_kernel<<<cgrid, dim3(TS, TS), 0, stream>>>(gray, comb, part);

    mul_kernel<<<N_IMG * 128, 256, 0, stream>>>((const float4*)x, (const float4*)comb,
                                                part, (fx4*)out);
}